// Round 3
// baseline (204.469 us; speedup 1.0000x reference)
//
#include <hip/hip_runtime.h>

#define BATCH 4096
#define NI 128
#define NH 256
#define NO 128
#define NG 17

static constexpr size_t EDGE_OFF  = (size_t)BATCH * NO;                    // 524288
static constexpr size_t BASIS_OFF = EDGE_OFF + (size_t)BATCH * NH * NO;    // 134742016
static constexpr size_t SCAL_OFF  = BASIS_OFF + (size_t)BATCH * NH * NG;   // 152567808

// degree-1 hat-spline taps at grid linspace(-2.5,2.5,17), spacing 0.3125
__device__ __forceinline__ void taps(float v, float& sil, float& wlo, float& whi,
                                     int& glo, int& ghi, float& u) {
    sil = v / (1.0f + __expf(-v));          // silu
    u   = (v + 2.5f) * 3.2f;                // (v - grid0)/spacing
    float kf = floorf(u);
    int   k  = (int)kf;
    float f  = u - kf;
    wlo = 1.0f - f;  whi = f;
    glo = k;         ghi = k + 1;
    if (glo < 0 || glo > 16) { glo = 0; wlo = 0.0f; }
    if (ghi < 0 || ghi > 16) { ghi = 0; whi = 0.0f; }
}

// ---------------- transpose (I,O,G) -> (I,G,O) ----------------
__global__ __launch_bounds__(256) void transpose_w(const float* __restrict__ w0,
                                                   const float* __restrict__ w1,
                                                   float* __restrict__ w0t,
                                                   float* __restrict__ w1t) {
    int j = blockIdx.x * 256 + threadIdx.x;
    const int total0 = NI * NG * NH;  // 557056
    if (j < total0) {
        int i = j / (NG * NH);
        int r = j - i * (NG * NH);
        int g = r / NH;
        int o = r - g * NH;
        w0t[j] = w0[((size_t)i * NH + o) * NG + g];
    } else {
        int jj = j - total0;
        int i = jj / (NG * NO);
        int r = jj - i * (NG * NO);
        int g = r / NO;
        int o = r - g * NO;
        w1t[jj] = w1[((size_t)i * NO + o) * NG + g];
    }
}

// ---------------- fused KAN -> LN -> KAN: one 128-thread block per row ----------------
__global__ __launch_bounds__(128) void kan_fused(
    const float* __restrict__ x,
    const float* __restrict__ bs0,
    const float* __restrict__ bias0,
    const float* __restrict__ bs1,
    const float* __restrict__ bias1,
    const float* __restrict__ gamma,
    const float* __restrict__ beta,
    const float* __restrict__ w0t,
    const float* __restrict__ w1t,
    float* __restrict__ out,
    float4* __restrict__ partials)
{
    __shared__ float s_sil0[NI], s_wlo0[NI], s_whi0[NI];
    __shared__ int   s_glo0[NI], s_ghi0[NI];
    __shared__ float s_sil1[NH], s_wlo1[NH], s_whi1[NH], s_u1[NH];
    __shared__ int   s_glo1[NH], s_ghi1[NH];
    __shared__ float s_red[128];
    __shared__ float4 s_out4[128];   // per-thread partial sums for its 4 o's
    __shared__ float4 s_red4[128];   // diagnostics

    const int tid = threadIdx.x;      // 0..127
    const int b   = blockIdx.x;

    // ---- layer-0 taps, i = tid ----
    {
        float xv = x[(size_t)b * NI + tid];
        float sil, wlo, whi, u; int glo, ghi;
        taps(xv, sil, wlo, whi, glo, ghi, u);
        s_sil0[tid] = sil; s_wlo0[tid] = wlo; s_whi0[tid] = whi;
        s_glo0[tid] = glo; s_ghi0[tid] = ghi;
    }
    __syncthreads();

    // ---- h for o = tid and o = tid+128 ----
    float h0 = 0.0f, h1 = 0.0f;
    for (int i = 0; i < NI; ++i) {
        const float sil = s_sil0[i], wlo = s_wlo0[i], whi = s_whi0[i];
        const float* bsr = bs0 + (size_t)i * NH;
        const float* wl  = w0t + (size_t)(i * NG + s_glo0[i]) * NH;
        const float* wh  = w0t + (size_t)(i * NG + s_ghi0[i]) * NH;
        h0 += sil * bsr[tid]       + wlo * wl[tid]       + whi * wh[tid];
        h1 += sil * bsr[tid + 128] + wlo * wl[tid + 128] + whi * wh[tid + 128];
    }
    h0 = h0 * 0.08838834764831844f + bias0[tid];        // 1/sqrt(128)
    h1 = h1 * 0.08838834764831844f + bias0[tid + 128];

    // ---- LayerNorm over 256 (2 values per thread) ----
    s_red[tid] = h0 + h1;
    __syncthreads();
    for (int s = 64; s > 0; s >>= 1) {
        if (tid < s) s_red[tid] += s_red[tid + s];
        __syncthreads();
    }
    const float mu = s_red[0] * (1.0f / NH);
    __syncthreads();
    const float d0 = h0 - mu, d1 = h1 - mu;
    s_red[tid] = d0 * d0 + d1 * d1;
    __syncthreads();
    for (int s = 64; s > 0; s >>= 1) {
        if (tid < s) s_red[tid] += s_red[tid + s];
        __syncthreads();
    }
    const float rs = rsqrtf(s_red[0] * (1.0f / NH) + 1e-5f);
    __syncthreads();
    const float hn0 = d0 * rs * gamma[tid]       + beta[tid];
    const float hn1 = d1 * rs * gamma[tid + 128] + beta[tid + 128];

    // ---- layer-1 taps for i = tid and i = tid+128 ----
    float bsum, bsq;
    {
        float sil, wlo, whi, u; int glo, ghi;
        taps(hn0, sil, wlo, whi, glo, ghi, u);
        s_sil1[tid] = sil; s_wlo1[tid] = wlo; s_whi1[tid] = whi;
        s_glo1[tid] = glo; s_ghi1[tid] = ghi; s_u1[tid] = u;
        bsum = wlo + whi;  bsq = wlo * wlo + whi * whi;
        taps(hn1, sil, wlo, whi, glo, ghi, u);
        s_sil1[tid + 128] = sil; s_wlo1[tid + 128] = wlo; s_whi1[tid + 128] = whi;
        s_glo1[tid + 128] = glo; s_ghi1[tid + 128] = ghi; s_u1[tid + 128] = u;
        bsum += wlo + whi; bsq += wlo * wlo + whi * whi;
    }
    __syncthreads();

    // ---- basis1: 256*17 = 4352 floats = 2176 float2 = 17 iters * 128 threads ----
    {
        float* bo = out + BASIS_OFF + (size_t)b * (NH * NG);
        #pragma unroll
        for (int it = 0; it < 17; ++it) {
            int j2 = it * 128 + tid;          // float2 index, 0..2175
            int f0 = j2 * 2;
            int i0 = f0 / NG,       g0 = f0 - i0 * NG;
            int i1 = (f0 + 1) / NG, g1 = (f0 + 1) - i1 * NG;
            float2 v;
            v.x = fmaxf(0.0f, 1.0f - fabsf(s_u1[i0] - (float)g0));
            v.y = fmaxf(0.0f, 1.0f - fabsf(s_u1[i1] - (float)g1));
            *reinterpret_cast<float2*>(bo + f0) = v;
        }
    }

    // ---- layer-1 edge loop: thread owns o-quad po..po+3, quarter of the i-range ----
    const int po = (tid & 31) * 4;
    const int q  = tid >> 5;            // i-quarter 0..3
    float4 osum = make_float4(0.f, 0.f, 0.f, 0.f);
    float esq = 0.0f;
    float* eo = out + EDGE_OFF + (size_t)b * (NH * NO);
    #pragma unroll 2
    for (int it = 0; it < 64; ++it) {
        const int i = q * 64 + it;
        const float sil = s_sil1[i], wlo = s_wlo1[i], whi = s_whi1[i];
        const float4 bsv = *reinterpret_cast<const float4*>(bs1 + (size_t)i * NO + po);
        const float4 wl  = *reinterpret_cast<const float4*>(w1t + (size_t)(i * NG + s_glo1[i]) * NO + po);
        const float4 wh  = *reinterpret_cast<const float4*>(w1t + (size_t)(i * NG + s_ghi1[i]) * NO + po);
        float4 e;
        e.x = sil * bsv.x + wlo * wl.x + whi * wh.x;
        e.y = sil * bsv.y + wlo * wl.y + whi * wh.y;
        e.z = sil * bsv.z + wlo * wl.z + whi * wh.z;
        e.w = sil * bsv.w + wlo * wl.w + whi * wh.w;
        *reinterpret_cast<float4*>(eo + (size_t)i * NO + po) = e;
        osum.x += e.x; osum.y += e.y; osum.z += e.z; osum.w += e.w;
        esq += e.x * e.x + e.y * e.y + e.z * e.z + e.w * e.w;
    }

    // ---- out row: combine the 4 i-quarters per o-quad ----
    s_out4[tid] = osum;
    __syncthreads();
    if (tid < 32) {
        float4 a = s_out4[tid], b2 = s_out4[tid + 32], c = s_out4[tid + 64], d2 = s_out4[tid + 96];
        const float4 bi = *reinterpret_cast<const float4*>(bias1 + tid * 4);
        float4 o4;
        o4.x = (a.x + b2.x + c.x + d2.x) * 0.0625f + bi.x;   // 1/sqrt(256)
        o4.y = (a.y + b2.y + c.y + d2.y) * 0.0625f + bi.y;
        o4.z = (a.z + b2.z + c.z + d2.z) * 0.0625f + bi.z;
        o4.w = (a.w + b2.w + c.w + d2.w) * 0.0625f + bi.w;
        *reinterpret_cast<float4*>(out + (size_t)b * NO + tid * 4) = o4;
    }

    // ---- diagnostics block reduce ----
    s_red4[tid] = make_float4(osum.x + osum.y + osum.z + osum.w, esq, bsum, bsq);
    __syncthreads();
    for (int s = 64; s > 0; s >>= 1) {
        if (tid < s) {
            float4 a = s_red4[tid], c = s_red4[tid + s];
            s_red4[tid] = make_float4(a.x + c.x, a.y + c.y, a.z + c.z, a.w + c.w);
        }
        __syncthreads();
    }
    if (tid == 0) partials[b] = s_red4[0];
}

// ---------------- deterministic final reduction of diagnostics ----------------
__global__ __launch_bounds__(256) void finalize(const float4* __restrict__ partials,
                                                float* __restrict__ out) {
    __shared__ double red[256];
    const int tid = threadIdx.x;
    double a0 = 0, a1 = 0, a2 = 0, a3 = 0;
    for (int j = tid; j < BATCH; j += 256) {
        float4 p = partials[j];
        a0 += (double)p.x; a1 += (double)p.y; a2 += (double)p.z; a3 += (double)p.w;
    }
    double tot[4];
    double v[4] = {a0, a1, a2, a3};
    for (int c = 0; c < 4; ++c) {
        red[tid] = v[c];
        __syncthreads();
        for (int s = 128; s > 0; s >>= 1) {
            if (tid < s) red[tid] += red[tid + s];
            __syncthreads();
        }
        tot[c] = red[0];
        __syncthreads();
    }
    if (tid == 0) {
        const double Ne = (double)BATCH * NH * NO;
        const double Nb = (double)BATCH * NH * NG;
        double me = tot[0] / Ne;
        double ve = tot[1] / Ne - me * me;
        double mb = tot[2] / Nb;
        double vb = tot[3] / Nb - mb * mb;
        out[SCAL_OFF + 0] = (float)me;
        out[SCAL_OFF + 1] = (float)sqrt(ve > 0.0 ? ve : 0.0);
        out[SCAL_OFF + 2] = (float)mb;
        out[SCAL_OFF + 3] = (float)sqrt(vb > 0.0 ? vb : 0.0);
    }
}

extern "C" void kernel_launch(void* const* d_in, const int* in_sizes, int n_in,
                              void* d_out, int out_size, void* d_ws, size_t ws_size,
                              hipStream_t stream) {
    const float* x     = (const float*)d_in[0];
    const float* bs0   = (const float*)d_in[1];
    const float* w0    = (const float*)d_in[2];
    const float* bias0 = (const float*)d_in[3];
    const float* bs1   = (const float*)d_in[4];
    const float* w1    = (const float*)d_in[5];
    const float* bias1 = (const float*)d_in[6];
    const float* gamma = (const float*)d_in[7];
    const float* beta  = (const float*)d_in[8];
    float* out = (float*)d_out;

    float*  w0t      = (float*)d_ws;                          // 557056 floats
    float*  w1t      = w0t + (size_t)NI * NG * NH;            // 557056 floats
    float4* partials = (float4*)(w1t + (size_t)NH * NG * NO); // 4096 float4

    hipLaunchKernelGGL(transpose_w, dim3(4352), dim3(256), 0, stream, w0, w1, w0t, w1t);
    hipLaunchKernelGGL(kan_fused, dim3(BATCH), dim3(128), 0, stream,
                       x, bs0, bias0, bs1, bias1, gamma, beta, w0t, w1t, out, partials);
    hipLaunchKernelGGL(finalize, dim3(1), dim3(256), 0, stream, partials, out);
}

// Round 5
// 164.033 us; speedup vs baseline: 1.2465x; 1.2465x over previous
//
#include <hip/hip_runtime.h>

#define BATCH 4096
#define NI 128
#define NH 256
#define NO 128
#define NG 17

static constexpr size_t EDGE_OFF  = (size_t)BATCH * NO;                    // 524288
static constexpr size_t BASIS_OFF = EDGE_OFF + (size_t)BATCH * NH * NO;    // 134742016
static constexpr size_t SCAL_OFF  = BASIS_OFF + (size_t)BATCH * NH * NG;   // 152567808

typedef float  vf2 __attribute__((ext_vector_type(2)));
typedef float  vf4 __attribute__((ext_vector_type(4)));

// round-to-nearest-even fp32 -> bf16 bits
__device__ __forceinline__ unsigned short f2bf(float v) {
    unsigned int b = __float_as_uint(v);
    b += 0x7FFFu + ((b >> 16) & 1u);
    return (unsigned short)(b >> 16);
}
__device__ __forceinline__ float bf2f(unsigned short u) {
    return __uint_as_float((unsigned int)u << 16);
}
// 4 packed bf16 (little-endian in uint2) -> float4
__device__ __forceinline__ float4 bf4_to_f4(uint2 v) {
    float4 r;
    r.x = __uint_as_float(v.x << 16);
    r.y = __uint_as_float(v.x & 0xFFFF0000u);
    r.z = __uint_as_float(v.y << 16);
    r.w = __uint_as_float(v.y & 0xFFFF0000u);
    return r;
}

// degree-1 hat-spline taps at grid linspace(-2.5,2.5,17), spacing 0.3125
__device__ __forceinline__ void taps(float v, float& sil, float& wlo, float& whi,
                                     int& glo, int& ghi, float& u) {
    sil = v / (1.0f + __expf(-v));          // silu
    u   = (v + 2.5f) * 3.2f;                // (v - grid0)/spacing
    float kf = floorf(u);
    int   k  = (int)kf;
    float f  = u - kf;
    wlo = 1.0f - f;  whi = f;
    glo = k;         ghi = k + 1;
    if (glo < 0 || glo > 16) { glo = 0; wlo = 0.0f; }
    if (ghi < 0 || ghi > 16) { ghi = 0; whi = 0.0f; }
}

// ---------------- transpose (I,O,G) -> (I,G,O) + bf16 convert; bs1 -> bf16 ----------------
__global__ __launch_bounds__(256) void transpose_convert(
    const float* __restrict__ w0, const float* __restrict__ w1,
    const float* __restrict__ bs1,
    unsigned short* __restrict__ w0t, unsigned short* __restrict__ w1t,
    unsigned short* __restrict__ bs1b) {
    int j = blockIdx.x * 256 + threadIdx.x;
    const int total0 = NI * NG * NH;  // 557056
    const int total1 = NH * NG * NO;  // 557056
    if (j < total0) {
        int i = j / (NG * NH);
        int r = j - i * (NG * NH);
        int g = r / NH;
        int o = r - g * NH;
        w0t[j] = f2bf(w0[((size_t)i * NH + o) * NG + g]);
    } else if (j < total0 + total1) {
        int jj = j - total0;
        int i = jj / (NG * NO);
        int r = jj - i * (NG * NO);
        int g = r / NO;
        int o = r - g * NO;
        w1t[jj] = f2bf(w1[((size_t)i * NO + o) * NG + g]);
    } else {
        int jj = j - total0 - total1;   // 0..32767
        bs1b[jj] = f2bf(bs1[jj]);
    }
}

// ---------------- fused KAN -> LN -> KAN: one 128-thread block per row ----------------
__global__ __launch_bounds__(128) void kan_fused(
    const float* __restrict__ x,
    const float* __restrict__ bs0,          // fp32 (LN-amplified path)
    const float* __restrict__ bias0,
    const unsigned short* __restrict__ bs1, // bf16
    const float* __restrict__ bias1,
    const float* __restrict__ gamma,
    const float* __restrict__ beta,
    const unsigned short* __restrict__ w0t, // bf16 (I,G,NH)
    const unsigned short* __restrict__ w1t, // bf16 (H,G,NO)
    float* __restrict__ out,
    float4* __restrict__ partials)
{
    __shared__ float s_sil0[NI], s_wlo0[NI], s_whi0[NI];
    __shared__ int   s_glo0[NI], s_ghi0[NI];
    __shared__ float s_sil1[NH], s_wlo1[NH], s_whi1[NH], s_u1[NH];
    __shared__ int   s_glo1[NH], s_ghi1[NH];
    __shared__ float s_red[128];
    __shared__ float4 s_out4[128];   // per-thread partial sums for its 4 o's
    __shared__ float4 s_red4[128];   // diagnostics

    const int tid = threadIdx.x;      // 0..127
    const int b   = blockIdx.x;

    // ---- layer-0 taps, i = tid ----
    {
        float xv = x[(size_t)b * NI + tid];
        float sil, wlo, whi, u; int glo, ghi;
        taps(xv, sil, wlo, whi, glo, ghi, u);
        s_sil0[tid] = sil; s_wlo0[tid] = wlo; s_whi0[tid] = whi;
        s_glo0[tid] = glo; s_ghi0[tid] = ghi;
    }
    __syncthreads();

    // ---- h for o = tid and o = tid+128 ----
    float h0 = 0.0f, h1 = 0.0f;
    for (int i = 0; i < NI; ++i) {
        const float sil = s_sil0[i], wlo = s_wlo0[i], whi = s_whi0[i];
        const float* bsr = bs0 + (size_t)i * NH;
        const unsigned short* wl = w0t + (size_t)(i * NG + s_glo0[i]) * NH;
        const unsigned short* wh = w0t + (size_t)(i * NG + s_ghi0[i]) * NH;
        h0 += sil * bsr[tid]       + wlo * bf2f(wl[tid])       + whi * bf2f(wh[tid]);
        h1 += sil * bsr[tid + 128] + wlo * bf2f(wl[tid + 128]) + whi * bf2f(wh[tid + 128]);
    }
    h0 = h0 * 0.08838834764831844f + bias0[tid];        // 1/sqrt(128)
    h1 = h1 * 0.08838834764831844f + bias0[tid + 128];

    // ---- LayerNorm over 256 (2 values per thread) ----
    s_red[tid] = h0 + h1;
    __syncthreads();
    for (int s = 64; s > 0; s >>= 1) {
        if (tid < s) s_red[tid] += s_red[tid + s];
        __syncthreads();
    }
    const float mu = s_red[0] * (1.0f / NH);
    __syncthreads();
    const float d0 = h0 - mu, d1 = h1 - mu;
    s_red[tid] = d0 * d0 + d1 * d1;
    __syncthreads();
    for (int s = 64; s > 0; s >>= 1) {
        if (tid < s) s_red[tid] += s_red[tid + s];
        __syncthreads();
    }
    const float rs = rsqrtf(s_red[0] * (1.0f / NH) + 1e-5f);
    __syncthreads();
    const float hn0 = d0 * rs * gamma[tid]       + beta[tid];
    const float hn1 = d1 * rs * gamma[tid + 128] + beta[tid + 128];

    // ---- layer-1 taps for i = tid and i = tid+128 ----
    float bsum, bsq;
    {
        float sil, wlo, whi, u; int glo, ghi;
        taps(hn0, sil, wlo, whi, glo, ghi, u);
        s_sil1[tid] = sil; s_wlo1[tid] = wlo; s_whi1[tid] = whi;
        s_glo1[tid] = glo; s_ghi1[tid] = ghi; s_u1[tid] = u;
        bsum = wlo + whi;  bsq = wlo * wlo + whi * whi;
        taps(hn1, sil, wlo, whi, glo, ghi, u);
        s_sil1[tid + 128] = sil; s_wlo1[tid + 128] = wlo; s_whi1[tid + 128] = whi;
        s_glo1[tid + 128] = glo; s_ghi1[tid + 128] = ghi; s_u1[tid + 128] = u;
        bsum += wlo + whi; bsq += wlo * wlo + whi * whi;
    }
    __syncthreads();

    // ---- basis1: 256*17 = 4352 floats = 2176 float2, nontemporal ----
    {
        float* bo = out + BASIS_OFF + (size_t)b * (NH * NG);
        #pragma unroll
        for (int it = 0; it < 17; ++it) {
            int j2 = it * 128 + tid;          // float2 index, 0..2175
            int f0 = j2 * 2;
            int i0 = f0 / NG,       g0 = f0 - i0 * NG;
            int i1 = (f0 + 1) / NG, g1 = (f0 + 1) - i1 * NG;
            vf2 v;
            v.x = fmaxf(0.0f, 1.0f - fabsf(s_u1[i0] - (float)g0));
            v.y = fmaxf(0.0f, 1.0f - fabsf(s_u1[i1] - (float)g1));
            __builtin_nontemporal_store(v, reinterpret_cast<vf2*>(bo + f0));
        }
    }

    // ---- layer-1 edge loop: thread owns o-quad po..po+3, quarter of the i-range ----
    const int po = (tid & 31) * 4;
    const int q  = tid >> 5;            // i-quarter 0..3
    float4 osum = make_float4(0.f, 0.f, 0.f, 0.f);
    float esq = 0.0f;
    float* eo = out + EDGE_OFF + (size_t)b * (NH * NO);
    #pragma unroll 2
    for (int it = 0; it < 64; ++it) {
        const int i = q * 64 + it;
        const float sil = s_sil1[i], wlo = s_wlo1[i], whi = s_whi1[i];
        const float4 bsv = bf4_to_f4(*reinterpret_cast<const uint2*>(bs1 + (size_t)i * NO + po));
        const float4 wl  = bf4_to_f4(*reinterpret_cast<const uint2*>(w1t + (size_t)(i * NG + s_glo1[i]) * NO + po));
        const float4 wh  = bf4_to_f4(*reinterpret_cast<const uint2*>(w1t + (size_t)(i * NG + s_ghi1[i]) * NO + po));
        vf4 e;
        e.x = sil * bsv.x + wlo * wl.x + whi * wh.x;
        e.y = sil * bsv.y + wlo * wl.y + whi * wh.y;
        e.z = sil * bsv.z + wlo * wl.z + whi * wh.z;
        e.w = sil * bsv.w + wlo * wl.w + whi * wh.w;
        __builtin_nontemporal_store(e, reinterpret_cast<vf4*>(eo + (size_t)i * NO + po));
        osum.x += e.x; osum.y += e.y; osum.z += e.z; osum.w += e.w;
        esq += e.x * e.x + e.y * e.y + e.z * e.z + e.w * e.w;
    }

    // ---- out row: combine the 4 i-quarters per o-quad ----
    s_out4[tid] = osum;
    __syncthreads();
    if (tid < 32) {
        float4 a = s_out4[tid], b2 = s_out4[tid + 32], c = s_out4[tid + 64], d2 = s_out4[tid + 96];
        const float4 bi = *reinterpret_cast<const float4*>(bias1 + tid * 4);
        float4 o4;
        o4.x = (a.x + b2.x + c.x + d2.x) * 0.0625f + bi.x;   // 1/sqrt(256)
        o4.y = (a.y + b2.y + c.y + d2.y) * 0.0625f + bi.y;
        o4.z = (a.z + b2.z + c.z + d2.z) * 0.0625f + bi.z;
        o4.w = (a.w + b2.w + c.w + d2.w) * 0.0625f + bi.w;
        *reinterpret_cast<float4*>(out + (size_t)b * NO + tid * 4) = o4;
    }

    // ---- diagnostics block reduce ----
    s_red4[tid] = make_float4(osum.x + osum.y + osum.z + osum.w, esq, bsum, bsq);
    __syncthreads();
    for (int s = 64; s > 0; s >>= 1) {
        if (tid < s) {
            float4 a = s_red4[tid], c = s_red4[tid + s];
            s_red4[tid] = make_float4(a.x + c.x, a.y + c.y, a.z + c.z, a.w + c.w);
        }
        __syncthreads();
    }
    if (tid == 0) partials[b] = s_red4[0];
}

// ---------------- deterministic final reduction of diagnostics ----------------
__global__ __launch_bounds__(256) void finalize(const float4* __restrict__ partials,
                                                float* __restrict__ out) {
    __shared__ double red[256];
    const int tid = threadIdx.x;
    double a0 = 0, a1 = 0, a2 = 0, a3 = 0;
    for (int j = tid; j < BATCH; j += 256) {
        float4 p = partials[j];
        a0 += (double)p.x; a1 += (double)p.y; a2 += (double)p.z; a3 += (double)p.w;
    }
    double tot[4];
    double v[4] = {a0, a1, a2, a3};
    for (int c = 0; c < 4; ++c) {
        red[tid] = v[c];
        __syncthreads();
        for (int s = 128; s > 0; s >>= 1) {
            if (tid < s) red[tid] += red[tid + s];
            __syncthreads();
        }
        tot[c] = red[0];
        __syncthreads();
    }
    if (tid == 0) {
        const double Ne = (double)BATCH * NH * NO;
        const double Nb = (double)BATCH * NH * NG;
        double me = tot[0] / Ne;
        double ve = tot[1] / Ne - me * me;
        double mb = tot[2] / Nb;
        double vb = tot[3] / Nb - mb * mb;
        out[SCAL_OFF + 0] = (float)me;
        out[SCAL_OFF + 1] = (float)sqrt(ve > 0.0 ? ve : 0.0);
        out[SCAL_OFF + 2] = (float)mb;
        out[SCAL_OFF + 3] = (float)sqrt(vb > 0.0 ? vb : 0.0);
    }
}

extern "C" void kernel_launch(void* const* d_in, const int* in_sizes, int n_in,
                              void* d_out, int out_size, void* d_ws, size_t ws_size,
                              hipStream_t stream) {
    const float* x     = (const float*)d_in[0];
    const float* bs0   = (const float*)d_in[1];
    const float* w0    = (const float*)d_in[2];
    const float* bias0 = (const float*)d_in[3];
    const float* bs1   = (const float*)d_in[4];
    const float* w1    = (const float*)d_in[5];
    const float* bias1 = (const float*)d_in[6];
    const float* gamma = (const float*)d_in[7];
    const float* beta  = (const float*)d_in[8];
    float* out = (float*)d_out;

    unsigned short* w0t  = (unsigned short*)d_ws;                 // 557056 bf16
    unsigned short* w1t  = w0t + (size_t)NI * NG * NH;            // 557056 bf16
    unsigned short* bs1b = w1t + (size_t)NH * NG * NO;            // 32768 bf16
    // align partials to 16B
    size_t ofs = ((size_t)(NI * NG * NH) + (size_t)(NH * NG * NO) + NH * NO) * sizeof(unsigned short);
    ofs = (ofs + 15) & ~(size_t)15;
    float4* partials = (float4*)((char*)d_ws + ofs);              // 4096 float4

    hipLaunchKernelGGL(transpose_convert, dim3(4480), dim3(256), 0, stream,
                       w0, w1, bs1, w0t, w1t, bs1b);
    hipLaunchKernelGGL(kan_fused, dim3(BATCH), dim3(128), 0, stream,
                       x, bs0, bias0, bs1b, bias1, gamma, beta, w0t, w1t, out, partials);
    hipLaunchKernelGGL(finalize, dim3(1), dim3(256), 0, stream, partials, out);
}